// Round 1
// baseline (588.965 us; speedup 1.0000x reference)
//
#include <hip/hip_runtime.h>
#include <math.h>
#include <float.h>
#include <limits.h>

#define N 8192
#define D 64
#define TOPK 32
#define TILE 128
#define CAP 1024      // old fallback path: per-wave LDS candidate cap
#define CAPC 512      // new path: per-row global candidate cap
#define NCHUNK 8      // column chunks in cand_zero (1024 cols each)

// orderable-uint encoding of float: a > b  <=>  ford(a) > ford(b)
__device__ __forceinline__ unsigned ford(float f) {
    unsigned u = __float_as_uint(f);
    return u ^ ((u & 0x80000000u) ? 0xFFFFFFFFu : 0x80000000u);
}
__device__ __forceinline__ float finv(unsigned u) {
    unsigned b = (u & 0x80000000u) ? (u ^ 0x80000000u) : ~u;
    return __uint_as_float(b);
}

// ---------------------------------------------------------------------------
// Kernel 1: row norms of X1 and X2 -> nrm[0..2N)
// ---------------------------------------------------------------------------
__global__ __launch_bounds__(256) void norms_kernel(
    const float* __restrict__ X1, const float* __restrict__ X2,
    float* __restrict__ nrm)
{
    int id = blockIdx.x * blockDim.x + threadIdx.x;
    if (id >= 2 * N) return;
    const float* X = (id < N) ? X1 : X2;
    int r = (id < N) ? id : id - N;
    const float4* p = (const float4*)(X + (size_t)r * D);
    float s = 0.f;
#pragma unroll
    for (int q = 0; q < D / 4; ++q) {
        float4 v = p[q];
        s += v.x * v.x + v.y * v.y + v.z * v.z + v.w * v.w;
    }
    nrm[id] = s;
}

// ---------------------------------------------------------------------------
// NEW Kernel 2: GEMM pass that emits ONLY per-(row,tile) maxes of
// v = -max(sq,0) (monotone proxy for -sqrt). 2 MB instead of 268 MB.
// Same 128x128 tile / 8x8 micro-tile / XOR-swizzle as the proven dist kernel.
// ---------------------------------------------------------------------------
__global__ __launch_bounds__(256, 2) void dist_tmax_kernel(
    const float* __restrict__ X1, const float* __restrict__ X2,
    const float* __restrict__ nrm, float* __restrict__ tmax)
{
    __shared__ float As[D * TILE];
    __shared__ float Bs[D * TILE];

    const int t = threadIdx.x;
    const int row0 = blockIdx.y * TILE;
    const int col0 = blockIdx.x * TILE;

#pragma unroll
    for (int p = 0; p < 8; ++p) {
        int lin = p * 256 + t;
        int r   = lin >> 4;
        int d4  = (lin & 15) << 2;
        int g   = (d4 >> 2) & 7;
        int cb  = r ^ (g << 3);
        float4 a = *(const float4*)(X1 + (size_t)(row0 + r) * D + d4);
        As[(d4 + 0) * TILE + cb] = a.x;
        As[(d4 + 1) * TILE + cb] = a.y;
        As[(d4 + 2) * TILE + cb] = a.z;
        As[(d4 + 3) * TILE + cb] = a.w;
        float4 b = *(const float4*)(X2 + (size_t)(col0 + r) * D + d4);
        Bs[(d4 + 0) * TILE + cb] = b.x;
        Bs[(d4 + 1) * TILE + cb] = b.y;
        Bs[(d4 + 2) * TILE + cb] = b.z;
        Bs[(d4 + 3) * TILE + cb] = b.w;
    }
    __syncthreads();

    const int tx = t & 15;
    const int ty = t >> 4;
    float acc[8][8] = {};

#pragma unroll 8
    for (int k = 0; k < D; ++k) {
        int gk  = (k >> 2) & 7;
        int ab  = k * TILE + ((ty ^ gk) << 3);
        int bb0 = k * TILE + ((4 * tx) ^ (gk << 3));
        float4 a0 = *(const float4*)&As[ab];
        float4 a1 = *(const float4*)&As[ab + 4];
        float4 b0 = *(const float4*)&Bs[bb0];
        float4 b1 = *(const float4*)&Bs[bb0 + 64];
        float av[8] = {a0.x, a0.y, a0.z, a0.w, a1.x, a1.y, a1.z, a1.w};
        float bv[8] = {b0.x, b0.y, b0.z, b0.w, b1.x, b1.y, b1.z, b1.w};
#pragma unroll
        for (int i = 0; i < 8; ++i)
#pragma unroll
            for (int j = 0; j < 8; ++j)
                acc[i][j] += av[i] * bv[j];
    }

    float na[8], nb[8];
#pragma unroll
    for (int i = 0; i < 8; ++i) na[i] = nrm[row0 + 8 * ty + i];
#pragma unroll
    for (int q = 0; q < 4; ++q) {
        nb[q]     = nrm[N + col0 + 4 * tx + q];
        nb[4 + q] = nrm[N + col0 + 64 + 4 * tx + q];
    }

#pragma unroll
    for (int i = 0; i < 8; ++i) {
        float mv = -FLT_MAX;
#pragma unroll
        for (int q = 0; q < 4; ++q) {
            float s0 = na[i] + nb[q] - 2.0f * acc[i][q];
            float v0 = -fmaxf(s0, 0.0f);
            float s1 = na[i] + nb[4 + q] - 2.0f * acc[i][4 + q];
            float v1 = -fmaxf(s1, 0.0f);
            mv = fmaxf(mv, fmaxf(v0, v1));
        }
        mv = fmaxf(mv, __shfl_down(mv, 8, 16));
        mv = fmaxf(mv, __shfl_down(mv, 4, 16));
        mv = fmaxf(mv, __shfl_down(mv, 2, 16));
        mv = fmaxf(mv, __shfl_down(mv, 1, 16));
        if (tx == 0)
            tmax[(size_t)(row0 + 8 * ty + i) * 64 + blockIdx.x] = mv;
    }
}

// ---------------------------------------------------------------------------
// NEW Kernel 2.5: per-row threshold = 32nd-largest tile max (sound lower
// bound on the 32nd-largest row value) minus 1e-3 margin; zero cnt[row].
// ---------------------------------------------------------------------------
__global__ __launch_bounds__(256) void thr_kernel(
    const float* __restrict__ tmax, float* __restrict__ thr,
    int* __restrict__ cnt)
{
    const int t = threadIdx.x;
    const int w = t >> 6;
    const int lane = t & 63;
    const int r = blockIdx.x * 4 + w;

    float tm = tmax[(size_t)r * 64 + lane];
    unsigned km = ford(tm);
    int rk = 0;
#pragma unroll
    for (int l = 0; l < 64; ++l) {
        unsigned o = __shfl(km, l);
        rk += (o > km || (o == km && l < lane)) ? 1 : 0;
    }
    unsigned long long bm = __ballot(rk == 31);
    float tv = __shfl(tm, __ffsll(bm) - 1);
    if (lane == 0) {
        thr[r] = tv - 1e-3f;   // margin: recompute need not be bitwise equal
        cnt[r] = 0;
    }
}

// ---------------------------------------------------------------------------
// NEW Kernel 3: recompute the GEMM (identical FMA ordering), write ZEROS to
// out in place of distances, append survivors (v >= thr, ~44/row expected)
// to a global per-row candidate buffer. A-tile staged once per block; B
// re-staged per column tile (8 tiles of 128 per block).
// ---------------------------------------------------------------------------
__global__ __launch_bounds__(256, 2) void cand_zero_kernel(
    const float* __restrict__ X1, const float* __restrict__ X2,
    const float* __restrict__ nrm, const float* __restrict__ thr,
    float* __restrict__ out, unsigned long long* __restrict__ cand,
    int* __restrict__ cnt)
{
    __shared__ float As[D * TILE];
    __shared__ float Bs[D * TILE];

    const int t = threadIdx.x;
    const int row0 = blockIdx.y * TILE;
    const int chunk0 = blockIdx.x * (N / NCHUNK);
    const int tx = t & 15;
    const int ty = t >> 4;

    // stage A once: rows fixed for the whole block
#pragma unroll
    for (int p = 0; p < 8; ++p) {
        int lin = p * 256 + t;
        int r   = lin >> 4;
        int d4  = (lin & 15) << 2;
        int g   = (d4 >> 2) & 7;
        int cb  = r ^ (g << 3);
        float4 a = *(const float4*)(X1 + (size_t)(row0 + r) * D + d4);
        As[(d4 + 0) * TILE + cb] = a.x;
        As[(d4 + 1) * TILE + cb] = a.y;
        As[(d4 + 2) * TILE + cb] = a.z;
        As[(d4 + 3) * TILE + cb] = a.w;
    }

    float na[8], thv[8];
#pragma unroll
    for (int i = 0; i < 8; ++i) {
        na[i]  = nrm[row0 + 8 * ty + i];
        thv[i] = thr[row0 + 8 * ty + i];
    }
    __syncthreads();

    for (int ct = 0; ct < (N / NCHUNK) / TILE; ++ct) {
        const int col0 = chunk0 + ct * TILE;
        if (ct) __syncthreads();   // previous iteration's Bs readers done
#pragma unroll
        for (int p = 0; p < 8; ++p) {
            int lin = p * 256 + t;
            int r   = lin >> 4;
            int d4  = (lin & 15) << 2;
            int g   = (d4 >> 2) & 7;
            int cb  = r ^ (g << 3);
            float4 b = *(const float4*)(X2 + (size_t)(col0 + r) * D + d4);
            Bs[(d4 + 0) * TILE + cb] = b.x;
            Bs[(d4 + 1) * TILE + cb] = b.y;
            Bs[(d4 + 2) * TILE + cb] = b.z;
            Bs[(d4 + 3) * TILE + cb] = b.w;
        }
        __syncthreads();

        float acc[8][8] = {};
#pragma unroll 8
        for (int k = 0; k < D; ++k) {
            int gk  = (k >> 2) & 7;
            int ab  = k * TILE + ((ty ^ gk) << 3);
            int bb0 = k * TILE + ((4 * tx) ^ (gk << 3));
            float4 a0 = *(const float4*)&As[ab];
            float4 a1 = *(const float4*)&As[ab + 4];
            float4 b0 = *(const float4*)&Bs[bb0];
            float4 b1 = *(const float4*)&Bs[bb0 + 64];
            float av[8] = {a0.x, a0.y, a0.z, a0.w, a1.x, a1.y, a1.z, a1.w};
            float bv[8] = {b0.x, b0.y, b0.z, b0.w, b1.x, b1.y, b1.z, b1.w};
#pragma unroll
            for (int i = 0; i < 8; ++i)
#pragma unroll
                for (int j = 0; j < 8; ++j)
                    acc[i][j] += av[i] * bv[j];
        }

        float nb[8];
#pragma unroll
        for (int q = 0; q < 4; ++q) {
            nb[q]     = nrm[N + col0 + 4 * tx + q];
            nb[4 + q] = nrm[N + col0 + 64 + 4 * tx + q];
        }

        const float4 zz = make_float4(0.f, 0.f, 0.f, 0.f);
#pragma unroll
        for (int i = 0; i < 8; ++i) {
            const int row = row0 + 8 * ty + i;
            float* po = out + (size_t)row * N + col0 + 4 * tx;
            *(float4*)po        = zz;
            *(float4*)(po + 64) = zz;
#pragma unroll
            for (int q = 0; q < 8; ++q) {
                float s = na[i] + nb[q] - 2.0f * acc[i][q];
                float v = -fmaxf(s, 0.0f);
                if (v >= thv[i]) {
                    int col = col0 + ((q < 4) ? (4 * tx + q)
                                              : (64 + 4 * tx + (q - 4)));
                    int p0 = atomicAdd(&cnt[row], 1);
                    if (p0 < CAPC)
                        cand[(size_t)row * CAPC + p0] =
                            ((unsigned long long)ford(v) << 32) |
                            (unsigned)(8191 - col);
                }
            }
        }
    }
}

// ---------------------------------------------------------------------------
// NEW Kernel 4: one wave per row; exact top-32 from <=CAPC candidates,
// sqrt + softmax, scatter over the zeros written by kernel 3.
// ---------------------------------------------------------------------------
__global__ __launch_bounds__(256) void topk_scatter_kernel(
    float* __restrict__ out, float* __restrict__ score_out,
    const unsigned long long* __restrict__ cand, const int* __restrict__ cnt)
{
    __shared__ unsigned long long cs[4][CAPC];   // 16 KB
    const int t = threadIdx.x;
    const int w = t >> 6;
    const int lane = t & 63;
    const int r = blockIdx.x * 4 + w;

    int n = cnt[r];
    if (n > CAPC) n = CAPC;
    const unsigned long long* cr = cand + (size_t)r * CAPC;
    for (int q = lane; q < n; q += 64) cs[w][q] = cr[q];
    __builtin_amdgcn_s_waitcnt(0xC07F);   // lgkmcnt(0)

    unsigned long long mykey = 0ull;
    for (int it = 0; it < TOPK; ++it) {
        unsigned long long b = 0ull; int bp = 0;
        for (int q = lane; q < n; q += 64) {
            unsigned long long kk = cs[w][q];
            if (kk > b) { b = kk; bp = q; }
        }
        for (int off = 32; off > 0; off >>= 1) {
            unsigned long long ob = __shfl_down(b, off);
            int op = __shfl_down(bp, off);
            if (ob > b) { b = ob; bp = op; }
        }
        unsigned long long b0 = __shfl(b, 0);
        int bp0 = __shfl(bp, 0);
        if (lane == it) { mykey = b0; cs[w][bp0] = 0ull; }
    }

    float myv = 0.f; int myj = 0;
    if (lane < TOPK) {
        float sv = finv((unsigned)(mykey >> 32));   // stored -max(sq,0)
        myv = -sqrtf(-sv);
        myj = 8191 - (int)(mykey & 0xFFFFFFFFu);
    }
    float Mx = __shfl(myv, 0);
    float e = (lane < TOPK) ? expf(myv - Mx) : 0.f;
    float Z = e;
    for (int off = 32; off > 0; off >>= 1) Z += __shfl_xor(Z, off);
    float s = e / Z;
    if (lane < TOPK) {
        score_out[(size_t)r * TOPK + lane] = s;
        out[(size_t)r * N + myj] = s;    // zeros already laid down by kernel 3
    }
}

// ---------------------------------------------------------------------------
// FALLBACK path (workspace too small): previous verified pipeline.
// ---------------------------------------------------------------------------
__global__ __launch_bounds__(256, 2) void dist_kernel(
    const float* __restrict__ X1, const float* __restrict__ X2,
    const float* __restrict__ nrm, float* __restrict__ out,
    float* __restrict__ tmax, int have_tmax)
{
    __shared__ float As[D * TILE];
    __shared__ float Bs[D * TILE];

    const int t = threadIdx.x;
    const int row0 = blockIdx.y * TILE;
    const int col0 = blockIdx.x * TILE;

#pragma unroll
    for (int p = 0; p < 8; ++p) {
        int lin = p * 256 + t;
        int r   = lin >> 4;
        int d4  = (lin & 15) << 2;
        int g   = (d4 >> 2) & 7;
        int cb  = r ^ (g << 3);
        float4 a = *(const float4*)(X1 + (size_t)(row0 + r) * D + d4);
        As[(d4 + 0) * TILE + cb] = a.x;
        As[(d4 + 1) * TILE + cb] = a.y;
        As[(d4 + 2) * TILE + cb] = a.z;
        As[(d4 + 3) * TILE + cb] = a.w;
        float4 b = *(const float4*)(X2 + (size_t)(col0 + r) * D + d4);
        Bs[(d4 + 0) * TILE + cb] = b.x;
        Bs[(d4 + 1) * TILE + cb] = b.y;
        Bs[(d4 + 2) * TILE + cb] = b.z;
        Bs[(d4 + 3) * TILE + cb] = b.w;
    }
    __syncthreads();

    const int tx = t & 15;
    const int ty = t >> 4;
    float acc[8][8] = {};

#pragma unroll 8
    for (int k = 0; k < D; ++k) {
        int gk  = (k >> 2) & 7;
        int ab  = k * TILE + ((ty ^ gk) << 3);
        int bb0 = k * TILE + ((4 * tx) ^ (gk << 3));
        float4 a0 = *(const float4*)&As[ab];
        float4 a1 = *(const float4*)&As[ab + 4];
        float4 b0 = *(const float4*)&Bs[bb0];
        float4 b1 = *(const float4*)&Bs[bb0 + 64];
        float av[8] = {a0.x, a0.y, a0.z, a0.w, a1.x, a1.y, a1.z, a1.w};
        float bv[8] = {b0.x, b0.y, b0.z, b0.w, b1.x, b1.y, b1.z, b1.w};
#pragma unroll
        for (int i = 0; i < 8; ++i)
#pragma unroll
            for (int j = 0; j < 8; ++j)
                acc[i][j] += av[i] * bv[j];
    }

    float na[8], nb[8];
#pragma unroll
    for (int i = 0; i < 8; ++i) na[i] = nrm[row0 + 8 * ty + i];
#pragma unroll
    for (int q = 0; q < 4; ++q) {
        nb[q]     = nrm[N + col0 + 4 * tx + q];
        nb[4 + q] = nrm[N + col0 + 64 + 4 * tx + q];
    }

    float rmax[8];
#pragma unroll
    for (int i = 0; i < 8; ++i) rmax[i] = -FLT_MAX;

#pragma unroll
    for (int i = 0; i < 8; ++i) {
        float* po = out + (size_t)(row0 + 8 * ty + i) * N + col0 + 4 * tx;
        float4 o0, o1;
        float* f0 = (float*)&o0;
        float* f1 = (float*)&o1;
#pragma unroll
        for (int q = 0; q < 4; ++q) {
            float s0 = na[i] + nb[q] - 2.0f * acc[i][q];
            f0[q] = -fmaxf(s0, 0.0f);
            float s1 = na[i] + nb[4 + q] - 2.0f * acc[i][4 + q];
            f1[q] = -fmaxf(s1, 0.0f);
            rmax[i] = fmaxf(rmax[i], fmaxf(f0[q], f1[q]));
        }
        *(float4*)po        = o0;
        *(float4*)(po + 64) = o1;
    }

    if (have_tmax) {
#pragma unroll
        for (int i = 0; i < 8; ++i) {
            float mv = rmax[i];
            mv = fmaxf(mv, __shfl_down(mv, 8, 16));
            mv = fmaxf(mv, __shfl_down(mv, 4, 16));
            mv = fmaxf(mv, __shfl_down(mv, 2, 16));
            mv = fmaxf(mv, __shfl_down(mv, 1, 16));
            if (tx == 0)
                tmax[(size_t)(row0 + 8 * ty + i) * 64 + blockIdx.x] = mv;
        }
    }
}

__global__ __launch_bounds__(256) void topk_kernel(
    float* __restrict__ out, float* __restrict__ score_out,
    const float* __restrict__ tmax, int have_tmax)
{
    __shared__ unsigned long long cand[4][CAP];   // 32 KB
    __shared__ int scnt[4];

    const int t    = threadIdx.x;
    const int w    = t >> 6;
    const int lane = t & 63;
    const int r    = blockIdx.x * 4 + w;
    float* row = out + (size_t)r * N;
    const float4* row4 = (const float4*)row;

    float thr;
    float lm = -FLT_MAX;
    if (have_tmax) {
        float tm = tmax[(size_t)r * 64 + lane];
        unsigned km = ford(tm);
        int rk = 0;
#pragma unroll
        for (int l = 0; l < 64; ++l) {
            unsigned o = __shfl(km, l);
            rk += (o > km || (o == km && l < lane)) ? 1 : 0;
        }
        unsigned long long bm = __ballot(rk == 31);
        thr = __shfl(tm, __ffsll(bm) - 1);
    } else {
#pragma unroll 8
        for (int c = 0; c < 32; ++c) {
            float4 x = row4[c * 64 + lane];
            lm = fmaxf(lm, fmaxf(fmaxf(x.x, x.y), fmaxf(x.z, x.w)));
        }
        thr = lm;
        for (int off = 32; off > 0; off >>= 1)
            thr = fminf(thr, __shfl_xor(thr, off));
    }

    for (int attempt = 0; ; ++attempt) {
        if (lane == 0) scnt[w] = 0;
        __builtin_amdgcn_s_waitcnt(0xC07F);
        for (int c = 0; c < 32; ++c) {
            float4 x = row4[c * 64 + lane];
            float vs[4] = {x.x, x.y, x.z, x.w};
#pragma unroll
            for (int q = 0; q < 4; ++q) {
                float v = vs[q];
                lm = fmaxf(lm, v);
                if (v >= thr) {
                    int p = atomicAdd(&scnt[w], 1);
                    if (p < CAP) {
                        unsigned long long key =
                            ((unsigned long long)ford(v) << 32) |
                            (unsigned)(8191 - (4 * (c * 64 + lane) + q));
                        cand[w][p] = key;
                    }
                }
            }
        }
        __builtin_amdgcn_s_waitcnt(0xC07F);
        if (scnt[w] <= CAP || attempt == 1) break;
        unsigned kml = ford(lm);
        int rk2 = 0;
#pragma unroll
        for (int l = 0; l < 64; ++l) {
            unsigned o = __shfl(kml, l);
            rk2 += (o < kml || (o == kml && l < lane)) ? 1 : 0;
        }
        unsigned long long bm2 = __ballot(rk2 == 15);
        float t2 = __shfl(lm, __ffsll(bm2) - 1);
        thr = fmaxf(thr, t2);
    }
    const int n = min(scnt[w], CAP);

    unsigned long long mykey = 0ull;
    for (int it = 0; it < TOPK; ++it) {
        unsigned long long b = 0ull; int bp = 0;
        for (int q = lane; q < n; q += 64) {
            unsigned long long kk = cand[w][q];
            if (kk > b) { b = kk; bp = q; }
        }
        for (int off = 32; off > 0; off >>= 1) {
            unsigned long long ob = __shfl_down(b, off);
            int op = __shfl_down(bp, off);
            if (ob > b) { b = ob; bp = op; }
        }
        unsigned long long b0 = __shfl(b, 0);
        int bp0 = __shfl(bp, 0);
        if (lane == it) { mykey = b0; cand[w][bp0] = 0ull; }
    }

    float myv = 0.f; int myj = 0;
    if (lane < TOPK) {
        float sv = finv((unsigned)(mykey >> 32));
        myv = -sqrtf(-sv);
        myj = 8191 - (int)(mykey & 0xFFFFFFFFu);
    }
    float Mx = __shfl(myv, 0);
    float e = (lane < TOPK) ? expf(myv - Mx) : 0.f;
    float Z = e;
    for (int off = 32; off > 0; off >>= 1) Z += __shfl_xor(Z, off);
    float s = e / Z;
    if (lane < TOPK) score_out[(size_t)r * TOPK + lane] = s;

    const float4 zz = make_float4(0.f, 0.f, 0.f, 0.f);
#pragma unroll 8
    for (int c = 0; c < 32; ++c) ((float4*)row)[c * 64 + lane] = zz;
    __builtin_amdgcn_s_waitcnt(0x0F70);   // vmcnt(0)
    if (lane < TOPK) row[myj] = s;
}

// ---------------------------------------------------------------------------
extern "C" void kernel_launch(void* const* d_in, const int* in_sizes, int n_in,
                              void* d_out, int out_size, void* d_ws, size_t ws_size,
                              hipStream_t stream)
{
    const float* X1 = (const float*)d_in[0];
    const float* X2 = (const float*)d_in[1];
    float* out = (float*)d_out;
    float* score = out + (size_t)N * N;

    // workspace layout (new path):
    //   nrm  : 2N floats
    //   tmax : N*64 floats
    //   thr  : N floats
    //   cnt  : N ints
    //   cand : N*CAPC u64
    float* nrm  = (float*)d_ws;
    float* tmax = nrm + 2 * N;
    float* thrv = tmax + (size_t)N * 64;
    int*   cnt  = (int*)(thrv + N);
    unsigned long long* cand = (unsigned long long*)(cnt + N);

    size_t need_new = (size_t)(2 * N + (size_t)N * 64 + 2 * N) * sizeof(float)
                    + (size_t)N * CAPC * sizeof(unsigned long long);
    size_t need_old = (size_t)(2 * N + (size_t)N * 64) * sizeof(float);

    norms_kernel<<<(2 * N + 255) / 256, 256, 0, stream>>>(X1, X2, nrm);

    if (ws_size >= need_new) {
        dim3 grid(N / TILE, N / TILE);
        dist_tmax_kernel<<<grid, 256, 0, stream>>>(X1, X2, nrm, tmax);
        thr_kernel<<<N / 4, 256, 0, stream>>>(tmax, thrv, cnt);
        dim3 grid2(NCHUNK, N / TILE);
        cand_zero_kernel<<<grid2, 256, 0, stream>>>(X1, X2, nrm, thrv, out, cand, cnt);
        topk_scatter_kernel<<<N / 4, 256, 0, stream>>>(out, score, cand, cnt);
    } else {
        int have_tmax = (ws_size >= need_old) ? 1 : 0;
        dim3 grid(N / TILE, N / TILE);
        dist_kernel<<<grid, 256, 0, stream>>>(X1, X2, nrm, out, tmax, have_tmax);
        topk_kernel<<<N / 4, 256, 0, stream>>>(out, score, tmax, have_tmax);
    }
}